// Round 12
// baseline (103.397 us; speedup 1.0000x reference)
//
#include <hip/hip_runtime.h>
#include <math.h>

// Problem constants (Occ3D-nuScenes volume)
constexpr int   GX = 200, GY = 200, GZ = 16;
constexpr int   TOTAL = GX * GY * GZ;        // 640000 voxels
constexpr int   ND = 16;                     // feature dims
constexpr int   KW = 6;                      // reference window: start + [0,6)
constexpr float VS = 0.4f;
constexpr float VMINX = -40.0f, VMINY = -40.0f, VMINZ = -1.0f;

// Tiling: 4x4x8 voxel tiles; one WAVE per tile, two z-voxels per lane.
constexpr int   TS = 4;                      // x,y tile size
constexpr int   TSZ = 8;                     // z tile size (2 voxels/lane)
constexpr int   TX = 50, TY = 50, TZ = 2;    // 200/4, 200/4, 16/8
constexpr int   NT = TX * TY * TZ;           // 5000 tiles
constexpr int   RS = 20;                     // floats per record (80 B)
constexpr int   CAP = 128;                   // per-tile capacity (lambda~19, max<~80)
constexpr int   BR  = 12;                    // records per staged batch (12*80B)
constexpr float NHL2E = -0.72134752044448170f; // -0.5*log2(e): exp(-0.5*m) -> exp2(q)

typedef float v2f __attribute__((ext_vector_type(2)));

// Record layout (floats), 80 B:
//  [0..3]   mx, my, mz, opacity
//  [4..7]   q00, q01*2, q02*2, q11    (inverse cov pre-scaled by NHL2E)
//  [8..11]  q12*2, q22, s_packed, e_packed  (bbox packed 8b/axis)
//  [12..19] features as bf16 (RNE), 2 per uint
// d_out layout: [density: TOTAL floats][feats: TOTAL*ND floats]
// d_ws layout:  [gdata: n*RS floats][counts: NT][entries: NT*CAP]

__device__ __forceinline__ unsigned bf16_rne(float x) {
    unsigned u = __float_as_uint(x);
    return (u + 0x7fffu + ((u >> 16) & 1u)) >> 16;
}

// Shared bbox computation -- MUST be bit-identical between rec and bin roles.
__device__ __forceinline__ void bbox_of(float mx, float my, float mz,
                                        float a, float d, float f,
                                        int& sx, int& sy, int& sz,
                                        int& ex, int& ey, int& ez)
{
    float rx = 3.0f * sqrtf(a), ry = 3.0f * sqrtf(d), rz = 3.0f * sqrtf(f);
    sx = max(0, (int)((mx - rx - VMINX) / VS));     // trunc == .astype(int32)
    sy = max(0, (int)((my - ry - VMINY) / VS));
    sz = max(0, (int)((mz - rz - VMINZ) / VS));
    ex = min(GX, (int)((mx + rx - VMINX) / VS) + 1); ex = min(ex, sx + KW);
    ey = min(GY, (int)((my + ry - VMINY) / VS) + 1); ey = min(ey, sy + KW);
    ez = min(GZ, (int)((mz + rz - VMINZ) / VS) + 1); ez = min(ez, sz + KW);
}

// FUSED prep: one dispatch, role-split grid.
//  blocks [0, recBlocks):  record build, 1 gaussian/thread (streaming).
//  blocks [recBlocks, ..): binning, 1 thread per (gaussian, candidate-tile);
//     bbox recomputed from means/covs (NOT from gdata) -> the two roles are
//     data-independent and run CONCURRENTLY, removing the rec->bin dependency
//     and one launch gap. 8 candidates/gaussian (span<=4 voxels => <=2
//     tiles/axis); 8 lanes share one gaussian -> loads broadcast.
__global__ __launch_bounds__(256) void gv_prep(
    const float* __restrict__ means, const float* __restrict__ covs,
    const float* __restrict__ opac,  const float* __restrict__ feats,
    float* __restrict__ gdata, int* __restrict__ counts,
    int* __restrict__ entries, int n, int recBlocks)
{
    if ((int)blockIdx.x < recBlocks) {
        int g = blockIdx.x * 256 + threadIdx.x;
        if (g >= n) return;
        const float* cv = covs + (size_t)g * 9;
        // symmetric 3x3: [[a,b,c],[b,d,e],[c,e,f]]
        float a = cv[0], b = cv[1], c = cv[2], d = cv[4], e = cv[5], f = cv[8];
        float A = d * f - e * e;
        float B = c * e - b * f;
        float C = b * e - c * d;
        float invdet = 1.0f / (a * A + b * B + c * C);
        float mx = means[g * 3 + 0], my = means[g * 3 + 1], mz = means[g * 3 + 2];
        int sx, sy, sz, ex, ey, ez;
        bbox_of(mx, my, mz, a, d, f, sx, sy, sz, ex, ey, ez);

        float rec[RS];
        rec[0] = mx; rec[1] = my; rec[2] = mz; rec[3] = opac[g];
        rec[4] = (A * invdet) * NHL2E;                        // q00
        rec[5] = (B * invdet) * (2.0f * NHL2E);               // q01 (doubled)
        rec[6] = (C * invdet) * (2.0f * NHL2E);               // q02 (doubled)
        rec[7] = ((a * f - c * c) * invdet) * NHL2E;          // q11
        rec[8] = ((b * c - a * e) * invdet) * (2.0f * NHL2E); // q12 (doubled)
        rec[9] = ((a * d - b * b) * invdet) * NHL2E;          // q22
        rec[10] = __int_as_float(sx | (sy << 8) | (sz << 16));
        rec[11] = __int_as_float(ex | (ey << 8) | (ez << 16));
        const float* fr = feats + (size_t)g * ND;
#pragma unroll
        for (int q = 0; q < 8; ++q) {
            unsigned lo = bf16_rne(fr[2 * q]);
            unsigned hi = bf16_rne(fr[2 * q + 1]);
            rec[12 + q] = __uint_as_float(lo | (hi << 16));
        }
        float4* dst = (float4*)(gdata + (size_t)g * RS);   // 80B stride, 16B aligned
#pragma unroll
        for (int q = 0; q < 5; ++q) dst[q] = ((const float4*)rec)[q];
    } else {
        int gid = (blockIdx.x - recBlocks) * 256 + threadIdx.x;
        int g = gid >> 3;
        if (g >= n) return;
        int c = gid & 7;
        int dx = c & 1, dy = (c >> 1) & 1, dz = (c >> 2) & 1;

        const float* cv = covs + (size_t)g * 9;
        float a = cv[0], d = cv[4], f = cv[8];
        float mx = means[g * 3 + 0], my = means[g * 3 + 1], mz = means[g * 3 + 2];
        int sx, sy, sz, ex, ey, ez;
        bbox_of(mx, my, mz, a, d, f, sx, sy, sz, ex, ey, ez);

        int tx0 = sx >> 2, nx = ((ex - 1) >> 2) - tx0;   // {0,1}
        int ty0 = sy >> 2, ny = ((ey - 1) >> 2) - ty0;
        int tz0 = sz >> 3, nz = ((ez - 1) >> 3) - tz0;   // 8-voxel z-tiles

        if (dx <= nx && dy <= ny && dz <= nz) {
            int tile = ((tx0 + dx) * TY + (ty0 + dy)) * TZ + (tz0 + dz);
            int slot = atomicAdd(&counts[tile], 1);
            if (slot < CAP) entries[(size_t)tile * CAP + slot] = g;
        }
    }
}

// One WAVE per 4x4x8 tile; 2 voxels/lane (iz, iz+4). Records staged to LDS in
// 12-record batches (lanes 0..59 move one 16B chunk each), double-buffered,
// ids two batches ahead. Inner record loop now has a COMPILE-TIME trip count
// (BR=12, tail masked by wave-uniform `live`) -> full unroll: the compiler
// batches the 60 ds_read_b128s with counted lgkmcnt and interleaves 12
// records' VALU instead of serially exposing LDS latency per record.
__global__ __launch_bounds__(256) void gv_tile(
    const float* __restrict__ gdata, const int* __restrict__ counts,
    const int* __restrict__ entries, float* __restrict__ out)
{
    const int wv   = threadIdx.x >> 6;
    const int lane = threadIdx.x & 63;
    const int p    = blockIdx.x * 4 + wv;    // tile id 0..4999
    const int tz   = p & 1;                  // TZ = 2
    const int rem  = p >> 1;
    const int ty   = rem % TY;
    const int tx   = rem / TY;

    __shared__ float sbuf[4][2][BR * RS];    // 4 waves x double buffer x 960 B

    const int lz = lane & 3, ly = (lane >> 2) & 3, lx = lane >> 4;
    const int ix = tx * TS + lx, iy = ty * TS + ly;
    const int iz0 = tz * TSZ + lz, iz1 = iz0 + 4;
    const float pxc  = (float)ix  * VS + VMINX;   // voxel CORNER coords
    const float pyc  = (float)iy  * VS + VMINY;
    const float pzc0 = (float)iz0 * VS + VMINZ;
    const float pzc1 = pzc0 + 4.0f * VS;

    v2f accd2 = {0.0f, 0.0f};
    v2f accf2[ND];
#pragma unroll
    for (int c = 0; c < ND; ++c) accf2[c] = (v2f){0.0f, 0.0f};
    accf2[ND - 1] = (v2f){1e-5f, 1e-5f};        // grid_feats[:, -1] = 1e-5

    const int cnt = __builtin_amdgcn_readfirstlane(min(counts[p], CAP));
    const int* __restrict__ el = entries + (size_t)p * CAP;

    const int  rl = lane / 5;                  // record slot within batch (0..11)
    const int  fc = lane - rl * 5;             // 16B chunk within record (0..4)
    const bool stager = lane < 60;
    const int  wslot = rl * RS + fc * 4;       // float offset of this lane's chunk

    if (cnt > 0) {
        const int nb = (cnt + BR - 1) / BR;
        float* b0 = &sbuf[wv][0][0];
        float* b1 = &sbuf[wv][1][0];

        // Prologue: stage batch 0; prefetch batch 1 data + batch 2 ids.
        float4 vn; int idn2 = 0;
        if (stager) {
            int id0 = el[min(rl, cnt - 1)];
            float4 v0 = *(const float4*)(gdata + (size_t)id0 * RS + fc * 4);
            *(float4*)(b0 + wslot) = v0;
            int idn = el[min(BR + rl, cnt - 1)];
            vn = *(const float4*)(gdata + (size_t)idn * RS + fc * 4);
            idn2 = el[min(2 * BR + rl, cnt - 1)];
        }

        for (int b = 0; b < nb; ++b) {
            if (b + 1 < nb && stager) {
                float* dstb = ((b + 1) & 1) ? b1 : b0;
                *(float4*)(dstb + wslot) = vn;                // stage batch b+1
                vn = *(const float4*)(gdata + (size_t)idn2 * RS + fc * 4);
                idn2 = el[min((b + 3) * BR + rl, cnt - 1)];
            }
            const float* rb = (b & 1) ? b1 : b0;
            const int rbase = b * BR;
#pragma unroll
            for (int r = 0; r < BR; ++r) {                    // FULL UNROLL
                const bool live = (rbase + r) < cnt;          // wave-uniform tail mask
                const float* rec = rb + r * RS;               // wave-uniform -> broadcast
                float4 c2 = *(const float4*)(rec + 8);        // q12*2, q22, s_pk, e_pk
                int spk = __float_as_int(c2.z), epk = __float_as_int(c2.w);
                int sx = spk & 255, sy = (spk >> 8) & 255, sz = (spk >> 16) & 255;
                int ex = epk & 255, ey = (epk >> 8) & 255, ez = (epk >> 16) & 255;
                bool inxy = (ix >= sx) & (ix < ex) & (iy >= sy) & (iy < ey) & live;
                bool in0 = inxy & (iz0 >= sz) & (iz0 < ez);
                bool in1 = inxy & (iz1 >= sz) & (iz1 < ez);

                float4 c0 = *(const float4*)(rec);            // mx,my,mz,op
                float4 c1 = *(const float4*)(rec + 4);        // q00,q01*2,q02*2,q11
                float px  = pxc  - c0.x;
                float py  = pyc  - c0.y;
                float pz0 = pzc0 - c0.z;
                float pz1 = pzc1 - c0.z;
                // q(pz) = base + pz*(q22*pz + w): base,w shared across z pair
                float u    = fmaf(c1.x, px, c1.y * py);
                float base = fmaf(c1.w * py, py, px * u);
                float w    = fmaf(c2.x, py, c1.z * px);
                float q0   = fmaf(fmaf(c2.y, pz0, w), pz0, base);
                float q1   = fmaf(fmaf(c2.y, pz1, w), pz1, base);
                float d0 = c0.w * __builtin_amdgcn_exp2f(q0);
                float d1 = c0.w * __builtin_amdgcn_exp2f(q1);
                d0 = in0 ? d0 : 0.0f;
                d1 = in1 ? d1 : 0.0f;
                v2f dens2 = {d0, d1};
                accd2 += dens2;

                uint4 fA = *(const uint4*)(rec + 12);         // bf16 feats 0..7
                uint4 fB = *(const uint4*)(rec + 16);         // bf16 feats 8..15
#define BFLO(u) __uint_as_float((u) << 16)
#define BFHI(u) __uint_as_float((u) & 0xffff0000u)
#define ACC2(i, f) { float fv = (f); accf2[i] += dens2 * (v2f){fv, fv}; }
                ACC2(0,  BFLO(fA.x)); ACC2(1,  BFHI(fA.x));
                ACC2(2,  BFLO(fA.y)); ACC2(3,  BFHI(fA.y));
                ACC2(4,  BFLO(fA.z)); ACC2(5,  BFHI(fA.z));
                ACC2(6,  BFLO(fA.w)); ACC2(7,  BFHI(fA.w));
                ACC2(8,  BFLO(fB.x)); ACC2(9,  BFHI(fB.x));
                ACC2(10, BFLO(fB.y)); ACC2(11, BFHI(fB.y));
                ACC2(12, BFLO(fB.z)); ACC2(13, BFHI(fB.z));
                ACC2(14, BFLO(fB.w)); ACC2(15, BFHI(fB.w));
#undef ACC2
#undef BFLO
#undef BFHI
            }
        }
    }

    // Epilogue: two voxels per lane, each written exactly once.
    const int flat0 = (ix * GY + iy) * GZ + iz0;   // flat1 = flat0 + 4
    out[flat0]     = accd2.x;
    out[flat0 + 4] = accd2.y;
    float inv0 = 1.0f / fmaxf(accd2.x, 1e-6f);
    float inv1 = 1.0f / fmaxf(accd2.y, 1e-6f);
    float4* fo0 = (float4*)(out + TOTAL + (size_t)flat0 * ND);
    float4* fo1 = (float4*)(out + TOTAL + (size_t)(flat0 + 4) * ND);
#pragma unroll
    for (int q = 0; q < 4; ++q) {
        float4 w0, w1;
        w0.x = accf2[q * 4 + 0].x * inv0;  w1.x = accf2[q * 4 + 0].y * inv1;
        w0.y = accf2[q * 4 + 1].x * inv0;  w1.y = accf2[q * 4 + 1].y * inv1;
        w0.z = accf2[q * 4 + 2].x * inv0;  w1.z = accf2[q * 4 + 2].y * inv1;
        w0.w = accf2[q * 4 + 3].x * inv0;  w1.w = accf2[q * 4 + 3].y * inv1;
        fo0[q] = w0;
        fo1[q] = w1;
    }
}

extern "C" void kernel_launch(void* const* d_in, const int* in_sizes, int n_in,
                              void* d_out, int out_size, void* d_ws, size_t ws_size,
                              hipStream_t stream) {
    const float* means = (const float*)d_in[0];   // [N,3]
    const float* covs  = (const float*)d_in[1];   // [N,3,3]
    const float* opac  = (const float*)d_in[2];   // [N]
    const float* feats = (const float*)d_in[3];   // [N,16]
    float* out = (float*)d_out;                   // [TOTAL + TOTAL*ND]
    const int n = in_sizes[2];

    float* gdata   = (float*)d_ws;                            // n*RS floats (2.6 MB)
    int*   counts  = (int*)(gdata + (size_t)n * RS);          // NT ints
    int*   entries = counts + ((NT + 63) & ~63);              // NT*CAP ints (2.56 MB)

    const int recBlocks = (n + 255) / 256;                    // 128
    const int binBlocks = (n * 8 + 255) / 256;                // 1024

    hipMemsetAsync(counts, 0, NT * sizeof(int), stream);
    gv_prep<<<recBlocks + binBlocks, 256, 0, stream>>>(
        means, covs, opac, feats, gdata, counts, entries, n, recBlocks);
    gv_tile<<<NT / 4, 256, 0, stream>>>(gdata, counts, entries, out);
}